// Round 1
// baseline (603.988 us; speedup 1.0000x reference)
//
#include <hip/hip_runtime.h>
#include <math.h>

#define NF 128  // feature dim

// ---------------- LayerNorm + exact GELU ----------------
__global__ __launch_bounds__(64) void ln_gelu_kernel(
    const float* __restrict__ x, const float* __restrict__ gamma,
    const float* __restrict__ beta, float* __restrict__ out, int N)
{
    int node = blockIdx.x;
    if (node >= N) return;
    int t = threadIdx.x;
    const float* row = x + (size_t)node * NF;
    float a = row[t];
    float b = row[t + 64];
    float s = a + b, sq = a * a + b * b;
    #pragma unroll
    for (int m = 1; m <= 32; m <<= 1) {
        s  += __shfl_xor(s, m, 64);
        sq += __shfl_xor(sq, m, 64);
    }
    float mu  = s * (1.0f / 128.0f);
    float var = sq * (1.0f / 128.0f) - mu * mu;
    float rstd = rsqrtf(var + 1e-5f);
    float g0 = (a - mu) * rstd * gamma[t] + beta[t];
    float g1 = (b - mu) * rstd * gamma[t + 64] + beta[t + 64];
    // exact GELU: 0.5*x*(1+erf(x/sqrt(2)))
    g0 = 0.5f * g0 * (1.0f + erff(g0 * 0.70710678118654752f));
    g1 = 0.5f * g1 * (1.0f + erff(g1 * 0.70710678118654752f));
    float* o = out + (size_t)node * NF;
    o[t] = g0;
    o[t + 64] = g1;
}

// ---------------- Tiled fp32 GEMM: Y = (X @ W^T + bias) * scale + add ----------------
// X: [M,128], W: [128,128] row-major (out_dim major), Y: [M,128]
template<bool HAS_BIAS, bool HAS_ADD>
__global__ __launch_bounds__(256) void gemm128_kernel(
    const float* __restrict__ X, const float* __restrict__ W,
    const float* __restrict__ bias, const float* __restrict__ addm,
    float* __restrict__ Y, int M, float scale)
{
    __shared__ float Xs[64][128];   // row-major X tile, 32 KB
    __shared__ float Wl[32][128];   // transposed W chunk [k][col], 16 KB

    int tid = threadIdx.x;
    int m0 = blockIdx.x * 64;

    // load X tile (coalesced: 32 lanes x 16B = 512B per half-row)
    {
        int lr = tid & 31;   // k-quad
        int rr = tid >> 5;   // 0..7
        #pragma unroll
        for (int p = 0; p < 8; ++p) {
            int r = rr * 8 + p;
            int gm = m0 + r;
            float4 v = make_float4(0.f, 0.f, 0.f, 0.f);
            if (gm < M) v = *(const float4*)(X + (size_t)gm * NF + lr * 4);
            *(float4*)(&Xs[r][lr * 4]) = v;
        }
    }

    int tc = tid & 15, tr = tid >> 4;
    int c0 = tc * 8, r0 = tr * 4;
    float acc[4][8];
    #pragma unroll
    for (int i = 0; i < 4; ++i)
        #pragma unroll
        for (int j = 0; j < 8; ++j) acc[i][j] = 0.f;

    for (int kc = 0; kc < 4; ++kc) {
        __syncthreads();   // Xs ready (kc=0) / Wl readers done (kc>0)
        // load W chunk transposed; lanes span cols -> conflict-light LDS stores.
        // Global side is strided but W is 64KB L2-hot.
        {
            int col = tid & 127;
            int kh = (tid >> 7) * 16;   // 0 or 16
            #pragma unroll
            for (int s2 = 0; s2 < 4; ++s2) {
                int kk = kh + s2 * 4;
                float4 wv = *(const float4*)(W + (size_t)col * NF + kc * 32 + kk);
                Wl[kk + 0][col] = wv.x;
                Wl[kk + 1][col] = wv.y;
                Wl[kk + 2][col] = wv.z;
                Wl[kk + 3][col] = wv.w;
            }
        }
        __syncthreads();

        #pragma unroll
        for (int k4 = 0; k4 < 32; k4 += 4) {
            float4 xq[4];
            #pragma unroll
            for (int i = 0; i < 4; ++i)
                xq[i] = *(const float4*)(&Xs[r0 + i][kc * 32 + k4]);
            #pragma unroll
            for (int kk = 0; kk < 4; ++kk) {
                float4 wa = *(const float4*)(&Wl[k4 + kk][c0]);
                float4 wb = *(const float4*)(&Wl[k4 + kk][c0 + 4]);
                float wv8[8] = {wa.x, wa.y, wa.z, wa.w, wb.x, wb.y, wb.z, wb.w};
                #pragma unroll
                for (int i = 0; i < 4; ++i) {
                    float xv = (kk == 0) ? xq[i].x : (kk == 1) ? xq[i].y
                             : (kk == 2) ? xq[i].z : xq[i].w;
                    #pragma unroll
                    for (int j = 0; j < 8; ++j)
                        acc[i][j] += xv * wv8[j];
                }
            }
        }
    }

    #pragma unroll
    for (int i = 0; i < 4; ++i) {
        int gm = m0 + r0 + i;
        if (gm >= M) continue;
        size_t base = (size_t)gm * NF + c0;
        #pragma unroll
        for (int j = 0; j < 8; ++j) {
            float v = acc[i][j];
            if (HAS_BIAS) v += bias[c0 + j];
            v *= scale;
            if (HAS_ADD) v += addm[base + j];
            Y[base + j] = v;
        }
    }
}

// ---------------- CSR build: histogram over src ----------------
__global__ void hist_kernel(const int* __restrict__ eid, int* __restrict__ cnt, int E)
{
    int i = blockIdx.x * blockDim.x + threadIdx.x;
    if (i < E) atomicAdd(&cnt[eid[i]], 1);   // row 0 = src
}

// ---------------- exclusive prefix sum (single block, wave-scan) ----------------
__global__ __launch_bounds__(1024) void scan_kernel(
    const int* __restrict__ cnt, int* __restrict__ row_start,
    int* __restrict__ cursor, int n)
{
    __shared__ int wsum[16];
    __shared__ int woff[17];
    int lane = threadIdx.x & 63;
    int w = threadIdx.x >> 6;
    int carry = 0;
    for (int base = 0; base < n; base += 1024) {
        int i = base + (int)threadIdx.x;
        int vv = (i < n) ? cnt[i] : 0;
        int s = vv;
        #pragma unroll
        for (int off = 1; off < 64; off <<= 1) {
            int t = __shfl_up(s, off, 64);
            if (lane >= off) s += t;
        }
        if (lane == 63) wsum[w] = s;
        __syncthreads();
        if (threadIdx.x == 0) {
            int a = 0;
            #pragma unroll
            for (int j2 = 0; j2 < 16; ++j2) { woff[j2] = a; a += wsum[j2]; }
            woff[16] = a;
        }
        __syncthreads();
        int excl = carry + woff[w] + (s - vv);
        if (i < n) { row_start[i] = excl; cursor[i] = excl; }
        carry += woff[16];
        __syncthreads();   // protect wsum/woff before next chunk
    }
    if (threadIdx.x == 0) row_start[n] = carry;
}

// ---------------- scatter edges into CSR order ----------------
__global__ void scatter_kernel(const int* __restrict__ eid, const float* __restrict__ ew,
                               int* __restrict__ cursor, int* __restrict__ sdst,
                               float* __restrict__ sw, int E)
{
    int i = blockIdx.x * blockDim.x + threadIdx.x;
    if (i < E) {
        int src = eid[i];
        int dst = eid[E + i];
        int pos = atomicAdd(&cursor[src], 1);
        sdst[pos] = dst;
        sw[pos] = ew[i];
    }
}

// ---------------- per-node attention aggregation (atomic-free) ----------------
__global__ __launch_bounds__(128) void aggregate_kernel(
    const float* __restrict__ Q, const float* __restrict__ Kf,
    const float* __restrict__ V, const int* __restrict__ row_start,
    const int* __restrict__ sdst, const float* __restrict__ sw,
    float* __restrict__ agg, int N)
{
    int node = blockIdx.x;
    if (node >= N) return;
    int t = threadIdx.x;
    float q = Q[(size_t)node * NF + t];   // q already has /sqrt(hd)
    int rs = row_start[node], re = row_start[node + 1];
    float acc = 0.f;
    for (int i = rs; i < re; ++i) {
        int dst = sdst[i];
        float w = sw[i];
        float p = q * Kf[(size_t)dst * NF + t];
        // reduce within 16-lane head group (heads align with wave64 lanes)
        p += __shfl_xor(p, 1, 64);
        p += __shfl_xor(p, 2, 64);
        p += __shfl_xor(p, 4, 64);
        p += __shfl_xor(p, 8, 64);
        float a = w / (1.0f + __expf(-p));
        acc += a * V[(size_t)dst * NF + t];
    }
    agg[(size_t)node * NF + t] = acc;
}

extern "C" void kernel_launch(void* const* d_in, const int* in_sizes, int n_in,
                              void* d_out, int out_size, void* d_ws, size_t ws_size,
                              hipStream_t stream)
{
    const float* in_feats = (const float*)d_in[0];
    const float* struc    = (const float*)d_in[1];
    const float* eweights = (const float*)d_in[2];
    const float* ln_scale = (const float*)d_in[3];
    const float* ln_bias  = (const float*)d_in[4];
    const float* Ws       = (const float*)d_in[5];
    const float* bs       = (const float*)d_in[6];
    const float* Wq       = (const float*)d_in[7];
    const float* bq       = (const float*)d_in[8];
    const float* Wk       = (const float*)d_in[9];
    const float* bk       = (const float*)d_in[10];
    const float* Wv       = (const float*)d_in[11];
    const float* bv       = (const float*)d_in[12];
    const float* Wo       = (const float*)d_in[13];
    const int*   edge_ids = (const int*)d_in[14];
    float* out = (float*)d_out;

    int N = in_sizes[0] / NF;     // 50000
    int E = in_sizes[2];          // 800000

    // workspace layout (fp32 buffers of N*128, then int region)
    size_t F = (size_t)N * NF;
    float* delta = (float*)d_ws;
    float* dstr  = delta + F;
    float* q     = dstr + F;
    float* kbuf  = q + F;
    float* v     = kbuf + F;
    float* agg   = v + F;
    int*   cnt       = (int*)(agg + F);
    int*   row_start = cnt + N;            // N+1 entries
    int*   cursor    = row_start + N + 1;
    int*   sdst      = cursor + N;
    float* sw        = (float*)(sdst + E);

    int gb  = (N + 63) / 64;
    int geb = (E + 255) / 256;

    // 1. delta = gelu(layernorm(in_feats))
    ln_gelu_kernel<<<N, 64, 0, stream>>>(in_feats, ln_scale, ln_bias, delta, N);

    // 2. CSR build by src
    hipMemsetAsync(cnt, 0, (size_t)N * sizeof(int), stream);
    hist_kernel<<<geb, 256, 0, stream>>>(edge_ids, cnt, E);
    scan_kernel<<<1, 1024, 0, stream>>>(cnt, row_start, cursor, N);
    scatter_kernel<<<geb, 256, 0, stream>>>(edge_ids, eweights, cursor, sdst, sw, E);

    // 3. node transforms
    // delta_struc = delta + struc @ Ws^T + bs
    gemm128_kernel<true, true ><<<gb, 256, 0, stream>>>(struc, Ws, bs, delta, dstr, N, 1.0f);
    // val = delta @ Wv^T + bv
    gemm128_kernel<true, false><<<gb, 256, 0, stream>>>(delta, Wv, bv, nullptr, v, N, 1.0f);
    // qry = (delta_struc @ Wq^T + bq) / sqrt(16)
    gemm128_kernel<true, false><<<gb, 256, 0, stream>>>(dstr, Wq, bq, nullptr, q, N, 0.25f);
    // key = delta_struc @ Wk^T + bk
    gemm128_kernel<true, false><<<gb, 256, 0, stream>>>(dstr, Wk, bk, nullptr, kbuf, N, 1.0f);

    // 4. edge attention + segment sum (CSR, no atomics)
    aggregate_kernel<<<N, 128, 0, stream>>>(q, kbuf, v, row_start, sdst, sw, agg, N);

    // 5. out = in_feats + agg @ Wo^T
    gemm128_kernel<false, true><<<gb, 256, 0, stream>>>(agg, Wo, nullptr, in_feats, out, N, 1.0f);
}

// Round 2
// 372.447 us; speedup vs baseline: 1.6217x; 1.6217x over previous
//
#include <hip/hip_runtime.h>
#include <math.h>

#define NF 128

typedef __attribute__((ext_vector_type(8))) short short8;
typedef __attribute__((ext_vector_type(4))) float floatx4;

__device__ __forceinline__ unsigned short f2bf(float f) {
    union { float x; unsigned int i; } c; c.x = f;
    unsigned int r = c.i + 0x7fffu + ((c.i >> 16) & 1u);   // RNE
    return (unsigned short)(r >> 16);
}
__device__ __forceinline__ float bf2f(unsigned short u) {
    union { unsigned int i; float x; } c; c.i = ((unsigned int)u) << 16;
    return c.x;
}
__device__ __forceinline__ void unpack8(uint4 u, float* f) {
    union { unsigned int i; float x; } c;
    c.i = u.x << 16;          f[0] = c.x;
    c.i = u.x & 0xffff0000u;  f[1] = c.x;
    c.i = u.y << 16;          f[2] = c.x;
    c.i = u.y & 0xffff0000u;  f[3] = c.x;
    c.i = u.z << 16;          f[4] = c.x;
    c.i = u.z & 0xffff0000u;  f[5] = c.x;
    c.i = u.w << 16;          f[6] = c.x;
    c.i = u.w & 0xffff0000u;  f[7] = c.x;
}

// ---------------- LayerNorm + exact GELU -> bf16 delta ----------------
__global__ __launch_bounds__(256) void ln_gelu_kernel(
    const float* __restrict__ x, const float* __restrict__ gamma,
    const float* __restrict__ beta, unsigned short* __restrict__ out, int N)
{
    int node = blockIdx.x * 4 + (threadIdx.x >> 6);
    if (node >= N) return;
    int t = threadIdx.x & 63;
    const float* row = x + (size_t)node * NF;
    float a = row[t];
    float b = row[t + 64];
    float s = a + b, sq = a * a + b * b;
    #pragma unroll
    for (int m = 1; m <= 32; m <<= 1) {
        s  += __shfl_xor(s, m, 64);
        sq += __shfl_xor(sq, m, 64);
    }
    float mu  = s * (1.0f / 128.0f);
    float var = sq * (1.0f / 128.0f) - mu * mu;
    float rstd = rsqrtf(var + 1e-5f);
    float g0 = (a - mu) * rstd * gamma[t] + beta[t];
    float g1 = (b - mu) * rstd * gamma[t + 64] + beta[t + 64];
    g0 = 0.5f * g0 * (1.0f + erff(g0 * 0.70710678118654752f));
    g1 = 0.5f * g1 * (1.0f + erff(g1 * 0.70710678118654752f));
    unsigned short* o = out + (size_t)node * NF;
    o[t] = f2bf(g0);
    o[t + 64] = f2bf(g1);
}

// ---------------- fp32 -> bf16 weight convert (5 matrices fused) --------
__global__ __launch_bounds__(256) void wconv5_kernel(
    const float* __restrict__ a, const float* __restrict__ b,
    const float* __restrict__ c, const float* __restrict__ d,
    const float* __restrict__ e, unsigned short* __restrict__ o)
{
    int i = blockIdx.x * 256 + threadIdx.x;       // 5*16384 total
    int w = i >> 14, j = i & 16383;
    const float* p = (w == 0) ? a : (w == 1) ? b : (w == 2) ? c : (w == 3) ? d : e;
    o[i] = f2bf(p[j]);
}

// ---------------- bf16 MFMA GEMM: Y = (X @ W^T + bias)*scale + add ------
// X:[M,128] (fp32 or bf16), W bf16 [128,128] row-major (out-dim major)
// block = 256 thr (4 waves), tile = 64 rows x 128 cols
template<int XF32, int ADDMODE, int OUTF32, bool HASB>
__global__ __launch_bounds__(256) void gemm_mfma_kernel(
    const void* __restrict__ Xv, const unsigned short* __restrict__ Wb,
    const float* __restrict__ bias, const void* __restrict__ addv,
    void* __restrict__ Yv, int M, float scale)
{
    // +8 bf16 row pad: ds_read_b128 lane stride 272B -> 2-way banks (free)
    __shared__ unsigned short Xs[64][136];
    __shared__ unsigned short Wl[128][136];
    int tid = threadIdx.x;
    int m0 = blockIdx.x * 64;

    // stage W (bf16, contiguous 32KB, coalesced uint4)
    {
        const uint4* Wg = (const uint4*)Wb;   // 2048 uint4 (16 per row)
        #pragma unroll
        for (int p = 0; p < 8; ++p) {
            int idx = tid + p * 256;
            int row = idx >> 4, c16 = idx & 15;
            uint4 u = Wg[idx];
            *(uint4*)&Wl[row][c16 * 8] = u;
        }
    }
    // stage X tile
    if (XF32) {
        const float* X = (const float*)Xv;
        #pragma unroll
        for (int p = 0; p < 8; ++p) {
            int idx = tid + p * 256;          // float4 units, 32 per row
            int row = idx >> 5, c4 = idx & 31;
            int gm = m0 + row;
            float4 f = make_float4(0.f, 0.f, 0.f, 0.f);
            if (gm < M) f = *(const float4*)(X + (size_t)gm * NF + c4 * 4);
            ushort4 h;
            h.x = f2bf(f.x); h.y = f2bf(f.y); h.z = f2bf(f.z); h.w = f2bf(f.w);
            *(ushort4*)&Xs[row][c4 * 4] = h;
        }
    } else {
        const uint4* X = (const uint4*)Xv;    // 16 uint4 per row
        #pragma unroll
        for (int p = 0; p < 4; ++p) {
            int idx = tid + p * 256;
            int row = idx >> 4, c16 = idx & 15;
            int gm = m0 + row;
            uint4 u = make_uint4(0u, 0u, 0u, 0u);
            if (gm < M) u = X[(size_t)gm * 16 + c16];
            *(uint4*)&Xs[row][c16 * 8] = u;
        }
    }
    __syncthreads();

    int lane = tid & 63, w = tid >> 6;
    int lg = lane & 15, quad = lane >> 4;
    int mrow = w * 16 + lg;

    floatx4 acc[8];
    #pragma unroll
    for (int t = 0; t < 8; ++t) acc[t] = (floatx4){0.f, 0.f, 0.f, 0.f};

    #pragma unroll
    for (int ks = 0; ks < 4; ++ks) {
        short8 a = *(const short8*)&Xs[mrow][ks * 32 + quad * 8];
        #pragma unroll
        for (int t = 0; t < 8; ++t) {
            short8 b = *(const short8*)&Wl[t * 16 + lg][ks * 32 + quad * 8];
            acc[t] = __builtin_amdgcn_mfma_f32_16x16x32_bf16(a, b, acc[t], 0, 0, 0);
        }
    }

    // C/D layout: col = lane&15 (per tile), row = quad*4 + reg
    #pragma unroll
    for (int t = 0; t < 8; ++t) {
        int col = t * 16 + lg;
        float bv_ = HASB ? bias[col] : 0.f;
        #pragma unroll
        for (int r = 0; r < 4; ++r) {
            int gm = m0 + w * 16 + quad * 4 + r;
            if (gm >= M) continue;
            float vv = (acc[t][r] + bv_) * scale;
            size_t off = (size_t)gm * NF + col;
            if (ADDMODE == 1) vv += bf2f(((const unsigned short*)addv)[off]);
            if (ADDMODE == 2) vv += ((const float*)addv)[off];
            if (OUTF32) ((float*)Yv)[off] = vv;
            else        ((unsigned short*)Yv)[off] = f2bf(vv);
        }
    }
}

// ---------------- CSR build ----------------
__global__ void hist_kernel(const int* __restrict__ eid, int* __restrict__ cnt, int E)
{
    int i = blockIdx.x * blockDim.x + threadIdx.x;
    if (i < E) atomicAdd(&cnt[eid[i]], 1);
}

// per-1024-chunk sums
__global__ __launch_bounds__(256) void scan1_kernel(
    const int* __restrict__ cnt, int* __restrict__ bsum, int n)
{
    int base = blockIdx.x * 1024;
    int s = 0;
    #pragma unroll
    for (int p = 0; p < 4; ++p) {
        int i = base + (int)threadIdx.x + p * 256;
        if (i < n) s += cnt[i];
    }
    #pragma unroll
    for (int m = 1; m <= 32; m <<= 1) s += __shfl_xor(s, m, 64);
    __shared__ int ws_[4];
    int wid = threadIdx.x >> 6;
    if ((threadIdx.x & 63) == 0) ws_[wid] = s;
    __syncthreads();
    if (threadIdx.x == 0) bsum[blockIdx.x] = ws_[0] + ws_[1] + ws_[2] + ws_[3];
}

// exclusive scan of block sums (nb <= 64), one wave
__global__ __launch_bounds__(64) void scan2_kernel(
    int* __restrict__ bsum, int* __restrict__ row_start, int nb, int n)
{
    int lane = threadIdx.x;
    int v = (lane < nb) ? bsum[lane] : 0;
    int s = v;
    #pragma unroll
    for (int off = 1; off < 64; off <<= 1) {
        int t = __shfl_up(s, off, 64);
        if (lane >= off) s += t;
    }
    if (lane < nb) bsum[lane] = s - v;     // exclusive
    if (lane == 63) row_start[n] = s;      // grand total
}

// rescan each chunk, write row_start + cursor
__global__ __launch_bounds__(256) void scan3_kernel(
    const int* __restrict__ cnt, const int* __restrict__ bsum,
    int* __restrict__ row_start, int* __restrict__ cursor, int n)
{
    int base = blockIdx.x * 1024;
    int tid = threadIdx.x, lane = tid & 63, wid = tid >> 6;
    int v[4]; int s = 0;
    #pragma unroll
    for (int p = 0; p < 4; ++p) {
        int i = base + tid * 4 + p;
        v[p] = (i < n) ? cnt[i] : 0;
        s += v[p];
    }
    int ss = s;
    #pragma unroll
    for (int off = 1; off < 64; off <<= 1) {
        int t = __shfl_up(ss, off, 64);
        if (lane >= off) ss += t;
    }
    __shared__ int wsum[4];
    if (lane == 63) wsum[wid] = ss;
    __syncthreads();
    int woff = 0;
    for (int j = 0; j < wid; ++j) woff += wsum[j];
    int a = bsum[blockIdx.x] + woff + (ss - s);
    #pragma unroll
    for (int p = 0; p < 4; ++p) {
        int i = base + tid * 4 + p;
        if (i < n) { row_start[i] = a; cursor[i] = a; a += v[p]; }
    }
}

__global__ void scatter_kernel(const int* __restrict__ eid, const float* __restrict__ ew,
                               int* __restrict__ cursor, int* __restrict__ sdst,
                               float* __restrict__ sw, int E)
{
    int i = blockIdx.x * blockDim.x + threadIdx.x;
    if (i < E) {
        int src = eid[i];
        int dst = eid[E + i];
        int pos = atomicAdd(&cursor[src], 1);
        sdst[pos] = dst;
        sw[pos] = ew[i];
    }
}

// ---------------- per-node attention aggregation ----------------
// 1 wave/node; 4 edges per iteration (16-lane subgroup per edge);
// lane covers 8 features via one dwordx4 bf16 load (256B/row, 2 lines).
__global__ __launch_bounds__(64) void aggregate_kernel(
    const unsigned short* __restrict__ Q, const unsigned short* __restrict__ Kf,
    const unsigned short* __restrict__ V, const int* __restrict__ row_start,
    const int* __restrict__ sdst, const float* __restrict__ sw,
    unsigned short* __restrict__ agg, int N)
{
    int node = blockIdx.x;
    int lane = threadIdx.x;
    int sg = lane >> 4, lg = lane & 15;
    int rs = row_start[node], re = row_start[node + 1];

    float qv[8];
    unpack8(*(const uint4*)(Q + (size_t)node * NF + lg * 8), qv);
    float acc[8];
    #pragma unroll
    for (int j = 0; j < 8; ++j) acc[j] = 0.f;

    for (int e0 = rs; e0 < re; e0 += 4) {
        int e = e0 + sg;
        bool valid = e < re;
        int ee = valid ? e : rs;
        int dst = sdst[ee];
        float w = valid ? sw[ee] : 0.f;

        float kv[8];
        unpack8(*(const uint4*)(Kf + (size_t)dst * NF + lg * 8), kv);
        float s = qv[0] * kv[0];
        #pragma unroll
        for (int j = 1; j < 8; ++j) s = fmaf(qv[j], kv[j], s);
        // head = 16 feats = 2 adjacent lanes (lg 2h, 2h+1)
        s += __shfl_xor(s, 1, 64);
        float a = w / (1.f + __expf(-s));

        float vv[8];
        unpack8(*(const uint4*)(V + (size_t)dst * NF + lg * 8), vv);
        #pragma unroll
        for (int j = 0; j < 8; ++j) acc[j] = fmaf(a, vv[j], acc[j]);
    }
    // sum the 4 subgroups
    #pragma unroll
    for (int j = 0; j < 8; ++j) {
        acc[j] += __shfl_xor(acc[j], 16, 64);
        acc[j] += __shfl_xor(acc[j], 32, 64);
    }
    if (sg == 0) {
        unsigned short* o = agg + (size_t)node * NF + lg * 8;
        ushort4 h0, h1;
        h0.x = f2bf(acc[0]); h0.y = f2bf(acc[1]); h0.z = f2bf(acc[2]); h0.w = f2bf(acc[3]);
        h1.x = f2bf(acc[4]); h1.y = f2bf(acc[5]); h1.z = f2bf(acc[6]); h1.w = f2bf(acc[7]);
        *(ushort4*)o = h0;
        *(ushort4*)(o + 4) = h1;
    }
}

extern "C" void kernel_launch(void* const* d_in, const int* in_sizes, int n_in,
                              void* d_out, int out_size, void* d_ws, size_t ws_size,
                              hipStream_t stream)
{
    const float* in_feats = (const float*)d_in[0];
    const float* struc    = (const float*)d_in[1];
    const float* eweights = (const float*)d_in[2];
    const float* ln_scale = (const float*)d_in[3];
    const float* ln_bias  = (const float*)d_in[4];
    const float* Ws       = (const float*)d_in[5];
    const float* bs       = (const float*)d_in[6];
    const float* Wq       = (const float*)d_in[7];
    const float* bq       = (const float*)d_in[8];
    const float* Wk       = (const float*)d_in[9];
    const float* bk       = (const float*)d_in[10];
    const float* Wv       = (const float*)d_in[11];
    const float* bv       = (const float*)d_in[12];
    const float* Wo       = (const float*)d_in[13];
    const int*   edge_ids = (const int*)d_in[14];
    float* out = (float*)d_out;

    int N = in_sizes[0] / NF;   // 50000
    int E = in_sizes[2];        // 800000

    // ---- workspace layout (bf16 feature buffers, then weights, then ints)
    size_t F = (size_t)N * NF;
    unsigned short* delta = (unsigned short*)d_ws;
    unsigned short* dstr  = delta + F;
    unsigned short* qb    = dstr + F;
    unsigned short* kb    = qb + F;
    unsigned short* vb    = kb + F;
    unsigned short* aggb  = vb + F;
    unsigned short* Wsb   = aggb + F;
    unsigned short* Wqb   = Wsb + 16384;
    unsigned short* Wkb   = Wqb + 16384;
    unsigned short* Wvb   = Wkb + 16384;
    unsigned short* Wob   = Wvb + 16384;
    int*   cnt       = (int*)(Wob + 16384);
    int*   row_start = cnt + N;          // N+1
    int*   cursor    = row_start + N + 1;
    int*   bsum      = cursor + N;       // 64
    int*   sdst      = bsum + 64;
    float* swv       = (float*)(sdst + E);

    int gb  = (N + 63) / 64;             // GEMM blocks (64 rows each)
    int geb = (E + 255) / 256;
    int nb  = (N + 1023) / 1024;         // scan chunks (49)

    // 1. delta = gelu(layernorm(in_feats)) -> bf16
    ln_gelu_kernel<<<(N + 3) / 4, 256, 0, stream>>>(in_feats, ln_scale, ln_bias, delta, N);
    // weights -> bf16 (order: Ws, Wq, Wk, Wv, Wo)
    wconv5_kernel<<<(5 * 16384) / 256, 256, 0, stream>>>(Ws, Wq, Wk, Wv, Wo, Wsb);

    // 2. CSR build by src
    hipMemsetAsync(cnt, 0, (size_t)N * sizeof(int), stream);
    hist_kernel<<<geb, 256, 0, stream>>>(edge_ids, cnt, E);
    scan1_kernel<<<nb, 256, 0, stream>>>(cnt, bsum, N);
    scan2_kernel<<<1, 64, 0, stream>>>(bsum, row_start, nb, N);
    scan3_kernel<<<nb, 256, 0, stream>>>(cnt, bsum, row_start, cursor, N);
    scatter_kernel<<<geb, 256, 0, stream>>>(edge_ids, eweights, cursor, sdst, swv, E);

    // 3. node transforms (bf16 MFMA)
    // dstr = delta + struc@Ws^T + bs   (X fp32, add bf16, out bf16)
    gemm_mfma_kernel<1, 1, 0, true><<<gb, 256, 0, stream>>>(struc, Wsb, bs, delta, dstr, N, 1.0f);
    // v = delta@Wv^T + bv
    gemm_mfma_kernel<0, 0, 0, true><<<gb, 256, 0, stream>>>(delta, Wvb, bv, nullptr, vb, N, 1.0f);
    // q = (dstr@Wq^T + bq) / 4
    gemm_mfma_kernel<0, 0, 0, true><<<gb, 256, 0, stream>>>(dstr, Wqb, bq, nullptr, qb, N, 0.25f);
    // k = dstr@Wk^T + bk
    gemm_mfma_kernel<0, 0, 0, true><<<gb, 256, 0, stream>>>(dstr, Wkb, bk, nullptr, kb, N, 1.0f);

    // 4. edge attention + segment-sum (CSR, no atomics) -> bf16 agg
    aggregate_kernel<<<N, 64, 0, stream>>>(qb, kb, vb, row_start, sdst, swv, aggb, N);

    // 5. out = in_feats + agg@Wo^T  (X bf16, add fp32, out fp32)
    gemm_mfma_kernel<0, 2, 1, false><<<gb, 256, 0, stream>>>(aggb, Wob, nullptr, in_feats, out, N, 1.0f);
}

// Round 3
// 328.528 us; speedup vs baseline: 1.8385x; 1.1337x over previous
//
#include <hip/hip_runtime.h>
#include <math.h>

#define NF 128

typedef __attribute__((ext_vector_type(8))) short short8;
typedef __attribute__((ext_vector_type(4))) float floatx4;

__device__ __forceinline__ unsigned short f2bf(float f) {
    union { float x; unsigned int i; } c; c.x = f;
    unsigned int r = c.i + 0x7fffu + ((c.i >> 16) & 1u);   // RNE
    return (unsigned short)(r >> 16);
}
__device__ __forceinline__ float bf2f(unsigned short u) {
    union { unsigned int i; float x; } c; c.i = ((unsigned int)u) << 16;
    return c.x;
}
__device__ __forceinline__ void unpack8(uint4 u, float* f) {
    union { unsigned int i; float x; } c;
    c.i = u.x << 16;          f[0] = c.x;
    c.i = u.x & 0xffff0000u;  f[1] = c.x;
    c.i = u.y << 16;          f[2] = c.x;
    c.i = u.y & 0xffff0000u;  f[3] = c.x;
    c.i = u.z << 16;          f[4] = c.x;
    c.i = u.z & 0xffff0000u;  f[5] = c.x;
    c.i = u.w << 16;          f[6] = c.x;
    c.i = u.w & 0xffff0000u;  f[7] = c.x;
}
__device__ __forceinline__ ushort4 pack4(float a, float b, float c, float d) {
    ushort4 h; h.x = f2bf(a); h.y = f2bf(b); h.z = f2bf(c); h.w = f2bf(d);
    return h;
}

// ---------------- fp32 -> bf16 weight convert (5 matrices) --------------
__global__ __launch_bounds__(256) void wconv5_kernel(
    const float* __restrict__ a, const float* __restrict__ b,
    const float* __restrict__ c, const float* __restrict__ d,
    const float* __restrict__ e, unsigned short* __restrict__ o)
{
    int i = blockIdx.x * 256 + threadIdx.x;       // 5*16384 total
    int w = i >> 14, j = i & 16383;
    const float* p = (w == 0) ? a : (w == 1) ? b : (w == 2) ? c : (w == 3) ? d : e;
    o[i] = f2bf(p[j]);
}

// ================= fused node transform ===============================
// one block = 64 node rows; LN+GELU -> delta; dstr = delta + struc@Ws^T+bs;
// q=(dstr@Wq+bq)/4, k=dstr@Wk+bk, v=delta@Wv+bv  (all bf16 MFMA)

__device__ __forceinline__ void stage_w64(unsigned short (*Wh)[136],
                                          const unsigned short* Wg, int tid)
{
    const uint4* g = (const uint4*)Wg;   // 1024 uint4 (64 rows x 16)
    #pragma unroll
    for (int p = 0; p < 4; ++p) {
        int idx = tid + p * 256;
        *(uint4*)&Wh[idx >> 4][(idx & 15) * 8] = g[idx];
    }
}

__device__ __forceinline__ void mfma4(const unsigned short (*A)[136],
                                      const unsigned short (*Wh)[136],
                                      int lg, int quad, int w, floatx4* acc4)
{
    #pragma unroll
    for (int ks = 0; ks < 4; ++ks) {
        short8 a = *(const short8*)&A[w * 16 + lg][ks * 32 + quad * 8];
        #pragma unroll
        for (int t = 0; t < 4; ++t) {
            short8 b = *(const short8*)&Wh[t * 16 + lg][ks * 32 + quad * 8];
            acc4[t] = __builtin_amdgcn_mfma_f32_16x16x32_bf16(a, b, acc4[t], 0, 0, 0);
        }
    }
}

// stage C-frags (bias+scale applied) into Wst rows 0..63, then coalesced copy out
__device__ __forceinline__ void emit_bf16(unsigned short (*Wst)[136],
                                          const floatx4* acc, const float* bias,
                                          float scale, unsigned short* outg,
                                          int m0, int M, int tid)
{
    int lane = tid & 63, w = tid >> 6, lg = lane & 15, quad = lane >> 4;
    __syncthreads();   // all waves done reading Wst as B before overwrite
    #pragma unroll
    for (int t = 0; t < 8; ++t) {
        int col = t * 16 + lg;
        float bvv = bias[col] * scale;
        #pragma unroll
        for (int r = 0; r < 4; ++r)
            Wst[w * 16 + quad * 4 + r][col] = f2bf(acc[t][r] * scale + bvv);
    }
    __syncthreads();
    #pragma unroll
    for (int p = 0; p < 4; ++p) {
        int idx = tid + p * 256;
        int row = idx >> 4, c16 = idx & 15;
        int gm = m0 + row;
        if (gm < M)
            *(uint4*)(outg + (size_t)gm * NF + c16 * 8) = *(const uint4*)&Wst[row][c16 * 8];
    }
    __syncthreads();   // copy reads done before Wst restage
}

__global__ __launch_bounds__(256) void fused_node_kernel(
    const float* __restrict__ in_feats, const float* __restrict__ struc,
    const float* __restrict__ gamma, const float* __restrict__ beta,
    const unsigned short* __restrict__ Wall,   // Ws,Wq,Wk,Wv bf16 (16384 each)
    const float* __restrict__ bs, const float* __restrict__ bq,
    const float* __restrict__ bk, const float* __restrict__ bv,
    unsigned short* __restrict__ qb, unsigned short* __restrict__ kb,
    unsigned short* __restrict__ vb, int M)
{
    __shared__ unsigned short Xd[64][136];    // delta (bf16)
    __shared__ unsigned short Xs2[64][136];   // struc -> dstr (bf16)
    __shared__ unsigned short Wl[64][136];    // weight half / output staging

    int tid = threadIdx.x;
    int m0 = blockIdx.x * 64;
    int lane = tid & 63, w = tid >> 6, lg = lane & 15, quad = lane >> 4;

    // ---- phase 0: stage Ws half0; LN+GELU -> Xd; struc -> Xs2
    stage_w64(Wl, Wall, tid);
    {
        int row = tid >> 2, t4 = tid & 3;   // 4 threads per row
        int gm = m0 + row;
        bool vr = gm < M;
        const float4* ip = (const float4*)(in_feats + (size_t)gm * NF) + t4 * 8;
        float4 xf[8];
        #pragma unroll
        for (int p = 0; p < 8; ++p)
            xf[p] = vr ? ip[p] : make_float4(0.f, 0.f, 0.f, 0.f);
        float s = 0.f, sq = 0.f;
        #pragma unroll
        for (int p = 0; p < 8; ++p) {
            s  += xf[p].x + xf[p].y + xf[p].z + xf[p].w;
            sq += xf[p].x * xf[p].x + xf[p].y * xf[p].y
                + xf[p].z * xf[p].z + xf[p].w * xf[p].w;
        }
        s  += __shfl_xor(s, 1, 64);  s  += __shfl_xor(s, 2, 64);
        sq += __shfl_xor(sq, 1, 64); sq += __shfl_xor(sq, 2, 64);
        float mu = s * (1.0f / 128.0f);
        float var = sq * (1.0f / 128.0f) - mu * mu;
        float rstd = rsqrtf(var + 1e-5f);
        const float4* gp = (const float4*)gamma + t4 * 8;
        const float4* bp = (const float4*)beta + t4 * 8;
        #pragma unroll
        for (int p = 0; p < 8; ++p) {
            float4 g4 = gp[p], b4 = bp[p];
            float o0 = (xf[p].x - mu) * rstd * g4.x + b4.x;
            float o1 = (xf[p].y - mu) * rstd * g4.y + b4.y;
            float o2 = (xf[p].z - mu) * rstd * g4.z + b4.z;
            float o3 = (xf[p].w - mu) * rstd * g4.w + b4.w;
            o0 = 0.5f * o0 * (1.0f + erff(o0 * 0.70710678118654752f));
            o1 = 0.5f * o1 * (1.0f + erff(o1 * 0.70710678118654752f));
            o2 = 0.5f * o2 * (1.0f + erff(o2 * 0.70710678118654752f));
            o3 = 0.5f * o3 * (1.0f + erff(o3 * 0.70710678118654752f));
            *(ushort4*)&Xd[row][t4 * 32 + p * 4] = pack4(o0, o1, o2, o3);
        }
        const float4* sp = (const float4*)(struc + (size_t)gm * NF) + t4 * 8;
        #pragma unroll
        for (int p = 0; p < 8; ++p) {
            float4 f = vr ? sp[p] : make_float4(0.f, 0.f, 0.f, 0.f);
            *(ushort4*)&Xs2[row][t4 * 32 + p * 4] = pack4(f.x, f.y, f.z, f.w);
        }
    }
    __syncthreads();

    floatx4 acc[8];
    #pragma unroll
    for (int t = 0; t < 8; ++t) acc[t] = (floatx4){0.f, 0.f, 0.f, 0.f};

    // ---- GEMM1: struc @ Ws^T  (A = Xs2)
    mfma4(Xs2, Wl, lg, quad, w, acc);
    __syncthreads();
    stage_w64(Wl, Wall + 8192, tid);          // Ws half1
    __syncthreads();
    mfma4(Xs2, Wl, lg, quad, w, acc + 4);
    __syncthreads();                          // B-reads done

    // writeback dstr = acc + bs + delta  -> Xs2 (own-wave rows only)
    #pragma unroll
    for (int t = 0; t < 8; ++t) {
        int col = t * 16 + lg;
        float bvv = bs[col];
        #pragma unroll
        for (int r = 0; r < 4; ++r) {
            int rl = w * 16 + quad * 4 + r;
            Xs2[rl][col] = f2bf(acc[t][r] + bvv + bf2f(Xd[rl][col]));
        }
    }
    stage_w64(Wl, Wall + 16384, tid);         // Wq half0 (independent of Xs2)
    __syncthreads();

    // ---- GEMM q
    #pragma unroll
    for (int t = 0; t < 8; ++t) acc[t] = (floatx4){0.f, 0.f, 0.f, 0.f};
    mfma4(Xs2, Wl, lg, quad, w, acc);
    __syncthreads();
    stage_w64(Wl, Wall + 16384 + 8192, tid);  // Wq half1
    __syncthreads();
    mfma4(Xs2, Wl, lg, quad, w, acc + 4);
    emit_bf16(Wl, acc, bq, 0.25f, qb, m0, M, tid);

    // ---- GEMM k
    stage_w64(Wl, Wall + 2 * 16384, tid);
    __syncthreads();
    #pragma unroll
    for (int t = 0; t < 8; ++t) acc[t] = (floatx4){0.f, 0.f, 0.f, 0.f};
    mfma4(Xs2, Wl, lg, quad, w, acc);
    __syncthreads();
    stage_w64(Wl, Wall + 2 * 16384 + 8192, tid);
    __syncthreads();
    mfma4(Xs2, Wl, lg, quad, w, acc + 4);
    emit_bf16(Wl, acc, bk, 1.0f, kb, m0, M, tid);

    // ---- GEMM v (A = Xd)
    stage_w64(Wl, Wall + 3 * 16384, tid);
    __syncthreads();
    #pragma unroll
    for (int t = 0; t < 8; ++t) acc[t] = (floatx4){0.f, 0.f, 0.f, 0.f};
    mfma4(Xd, Wl, lg, quad, w, acc);
    __syncthreads();
    stage_w64(Wl, Wall + 3 * 16384 + 8192, tid);
    __syncthreads();
    mfma4(Xd, Wl, lg, quad, w, acc + 4);
    emit_bf16(Wl, acc, bv, 1.0f, vb, m0, M, tid);
}

// ---------------- out-proj GEMM: out = in_feats + agg @ Wo^T ----------
__global__ __launch_bounds__(256) void gemm_out_kernel(
    const unsigned short* __restrict__ Xb, const unsigned short* __restrict__ Wb,
    const float* __restrict__ addf, float* __restrict__ Y, int M)
{
    __shared__ unsigned short Xs[64][136];
    __shared__ unsigned short Wl[128][136];
    int tid = threadIdx.x;
    int m0 = blockIdx.x * 64;

    {
        const uint4* Wg = (const uint4*)Wb;
        #pragma unroll
        for (int p = 0; p < 8; ++p) {
            int idx = tid + p * 256;
            *(uint4*)&Wl[idx >> 4][(idx & 15) * 8] = Wg[idx];
        }
    }
    {
        const uint4* X = (const uint4*)Xb;
        #pragma unroll
        for (int p = 0; p < 4; ++p) {
            int idx = tid + p * 256;
            int row = idx >> 4, c16 = idx & 15;
            int gm = m0 + row;
            uint4 u = make_uint4(0u, 0u, 0u, 0u);
            if (gm < M) u = X[(size_t)gm * 16 + c16];
            *(uint4*)&Xs[row][c16 * 8] = u;
        }
    }
    __syncthreads();

    int lane = tid & 63, w = tid >> 6, lg = lane & 15, quad = lane >> 4;
    floatx4 acc[8];
    #pragma unroll
    for (int t = 0; t < 8; ++t) acc[t] = (floatx4){0.f, 0.f, 0.f, 0.f};
    #pragma unroll
    for (int ks = 0; ks < 4; ++ks) {
        short8 a = *(const short8*)&Xs[w * 16 + lg][ks * 32 + quad * 8];
        #pragma unroll
        for (int t = 0; t < 8; ++t) {
            short8 b = *(const short8*)&Wl[t * 16 + lg][ks * 32 + quad * 8];
            acc[t] = __builtin_amdgcn_mfma_f32_16x16x32_bf16(a, b, acc[t], 0, 0, 0);
        }
    }
    #pragma unroll
    for (int t = 0; t < 8; ++t) {
        int col = t * 16 + lg;
        #pragma unroll
        for (int r = 0; r < 4; ++r) {
            int gm = m0 + w * 16 + quad * 4 + r;
            if (gm >= M) continue;
            size_t off = (size_t)gm * NF + col;
            Y[off] = acc[t][r] + addf[off];
        }
    }
}

// ---------------- CSR build ----------------
__global__ void hist_kernel(const int* __restrict__ eid, int* __restrict__ cnt, int E)
{
    int i = blockIdx.x * blockDim.x + threadIdx.x;
    if (i < E) atomicAdd(&cnt[eid[i]], 1);
}

__global__ __launch_bounds__(256) void scan1_kernel(
    const int* __restrict__ cnt, int* __restrict__ bsum, int n)
{
    int base = blockIdx.x * 1024;
    int s = 0;
    #pragma unroll
    for (int p = 0; p < 4; ++p) {
        int i = base + (int)threadIdx.x + p * 256;
        if (i < n) s += cnt[i];
    }
    #pragma unroll
    for (int m = 1; m <= 32; m <<= 1) s += __shfl_xor(s, m, 64);
    __shared__ int ws_[4];
    int wid = threadIdx.x >> 6;
    if ((threadIdx.x & 63) == 0) ws_[wid] = s;
    __syncthreads();
    if (threadIdx.x == 0) bsum[blockIdx.x] = ws_[0] + ws_[1] + ws_[2] + ws_[3];
}

__global__ __launch_bounds__(64) void scan2_kernel(
    int* __restrict__ bsum, int* __restrict__ row_start, int nb, int n)
{
    int lane = threadIdx.x;
    int v = (lane < nb) ? bsum[lane] : 0;
    int s = v;
    #pragma unroll
    for (int off = 1; off < 64; off <<= 1) {
        int t = __shfl_up(s, off, 64);
        if (lane >= off) s += t;
    }
    if (lane < nb) bsum[lane] = s - v;
    if (lane == 63) row_start[n] = s;
}

__global__ __launch_bounds__(256) void scan3_kernel(
    const int* __restrict__ cnt, const int* __restrict__ bsum,
    int* __restrict__ row_start, int* __restrict__ cursor, int n)
{
    int base = blockIdx.x * 1024;
    int tid = threadIdx.x, lane = tid & 63, wid = tid >> 6;
    int v[4]; int s = 0;
    #pragma unroll
    for (int p = 0; p < 4; ++p) {
        int i = base + tid * 4 + p;
        v[p] = (i < n) ? cnt[i] : 0;
        s += v[p];
    }
    int ss = s;
    #pragma unroll
    for (int off = 1; off < 64; off <<= 1) {
        int t = __shfl_up(ss, off, 64);
        if (lane >= off) ss += t;
    }
    __shared__ int wsum[4];
    if (lane == 63) wsum[wid] = ss;
    __syncthreads();
    int woff = 0;
    for (int j = 0; j < wid; ++j) woff += wsum[j];
    int a = bsum[blockIdx.x] + woff + (ss - s);
    #pragma unroll
    for (int p = 0; p < 4; ++p) {
        int i = base + tid * 4 + p;
        if (i < n) { row_start[i] = a; cursor[i] = a; a += v[p]; }
    }
}

__global__ void scatter_kernel(const int* __restrict__ eid, const float* __restrict__ ew,
                               int* __restrict__ cursor, int2* __restrict__ edata, int E)
{
    int i = blockIdx.x * blockDim.x + threadIdx.x;
    if (i < E) {
        int src = eid[i];
        int dst = eid[E + i];
        int pos = atomicAdd(&cursor[src], 1);
        edata[pos] = make_int2(dst, __float_as_int(ew[i]));
    }
}

// ---------------- per-node attention aggregation ----------------
__global__ __launch_bounds__(64) void aggregate_kernel(
    const unsigned short* __restrict__ Q, const unsigned short* __restrict__ Kf,
    const unsigned short* __restrict__ V, const int* __restrict__ row_start,
    const int2* __restrict__ edata, unsigned short* __restrict__ agg, int N)
{
    int node = blockIdx.x;
    int lane = threadIdx.x;
    int sg = lane >> 4, lg = lane & 15;
    int rs = row_start[node], re = row_start[node + 1];

    float qv[8];
    unpack8(*(const uint4*)(Q + (size_t)node * NF + lg * 8), qv);
    float acc[8];
    #pragma unroll
    for (int j = 0; j < 8; ++j) acc[j] = 0.f;

    int e = rs + sg;
    int2 ed = (e < re) ? edata[e] : make_int2(0, 0);
    for (int e0 = rs; e0 < re; e0 += 4) {
        int dst = ed.x;
        float wgt = __int_as_float(ed.y);
        int en = e0 + 4 + sg;
        int2 nxt = (en < re) ? edata[en] : make_int2(0, 0);

        float kv[8];
        unpack8(*(const uint4*)(Kf + (size_t)dst * NF + lg * 8), kv);
        float s = qv[0] * kv[0];
        #pragma unroll
        for (int j = 1; j < 8; ++j) s = fmaf(qv[j], kv[j], s);
        s += __shfl_xor(s, 1, 64);   // head = 16 feats = 2 adjacent lanes
        float a = wgt / (1.f + __expf(-s));

        float vv[8];
        unpack8(*(const uint4*)(V + (size_t)dst * NF + lg * 8), vv);
        #pragma unroll
        for (int j = 0; j < 8; ++j) acc[j] = fmaf(a, vv[j], acc[j]);
        ed = nxt;
    }
    #pragma unroll
    for (int j = 0; j < 8; ++j) {
        acc[j] += __shfl_xor(acc[j], 16, 64);
        acc[j] += __shfl_xor(acc[j], 32, 64);
    }
    if (sg == 0) {
        unsigned short* o = agg + (size_t)node * NF + lg * 8;
        *(ushort4*)o       = pack4(acc[0], acc[1], acc[2], acc[3]);
        *(ushort4*)(o + 4) = pack4(acc[4], acc[5], acc[6], acc[7]);
    }
}

extern "C" void kernel_launch(void* const* d_in, const int* in_sizes, int n_in,
                              void* d_out, int out_size, void* d_ws, size_t ws_size,
                              hipStream_t stream)
{
    const float* in_feats = (const float*)d_in[0];
    const float* struc    = (const float*)d_in[1];
    const float* eweights = (const float*)d_in[2];
    const float* ln_scale = (const float*)d_in[3];
    const float* ln_bias  = (const float*)d_in[4];
    const float* Ws       = (const float*)d_in[5];
    const float* bs       = (const float*)d_in[6];
    const float* Wq       = (const float*)d_in[7];
    const float* bq       = (const float*)d_in[8];
    const float* Wk       = (const float*)d_in[9];
    const float* bk       = (const float*)d_in[10];
    const float* Wv       = (const float*)d_in[11];
    const float* bv       = (const float*)d_in[12];
    const float* Wo       = (const float*)d_in[13];
    const int*   edge_ids = (const int*)d_in[14];
    float* out = (float*)d_out;

    int N = in_sizes[0] / NF;   // 50000
    int E = in_sizes[2];        // 800000

    // ---- workspace
    size_t F = (size_t)N * NF;
    unsigned short* qb   = (unsigned short*)d_ws;
    unsigned short* kb   = qb + F;
    unsigned short* vb   = kb + F;
    unsigned short* aggb = vb + F;
    unsigned short* Wall = aggb + F;            // 5*16384 bf16: Ws,Wq,Wk,Wv,Wo
    int2*  edata     = (int2*)(Wall + 5 * 16384);
    int*   cnt       = (int*)(edata + E);
    int*   row_start = cnt + N;                 // N+1
    int*   cursor    = row_start + N + 1;
    int*   bsum      = cursor + N;              // 64

    int gb  = (N + 63) / 64;
    int geb = (E + 255) / 256;
    int nb  = (N + 1023) / 1024;

    // weights -> bf16
    wconv5_kernel<<<(5 * 16384) / 256, 256, 0, stream>>>(Ws, Wq, Wk, Wv, Wo, Wall);

    // CSR build by src
    hipMemsetAsync(cnt, 0, (size_t)N * sizeof(int), stream);
    hist_kernel<<<geb, 256, 0, stream>>>(edge_ids, cnt, E);
    scan1_kernel<<<nb, 256, 0, stream>>>(cnt, bsum, N);
    scan2_kernel<<<1, 64, 0, stream>>>(bsum, row_start, nb, N);
    scan3_kernel<<<nb, 256, 0, stream>>>(cnt, bsum, row_start, cursor, N);
    scatter_kernel<<<geb, 256, 0, stream>>>(edge_ids, eweights, cursor, edata, E);

    // fused LN+GELU + 4 GEMMs -> q,k,v
    fused_node_kernel<<<gb, 256, 0, stream>>>(in_feats, struc, ln_scale, ln_bias,
                                              Wall, bs, bq, bk, bv, qb, kb, vb, N);

    // edge attention + segment-sum
    aggregate_kernel<<<N, 64, 0, stream>>>(qb, kb, vb, row_start, edata, aggb, N);

    // out = in_feats + agg @ Wo^T
    gemm_out_kernel<<<gb, 256, 0, stream>>>(aggb, Wall + 4 * 16384, in_feats, out, N);
}